// Round 1
// baseline (2210.472 us; speedup 1.0000x reference)
//
#include <hip/hip_runtime.h>
#include <cstddef>

constexpr int NB = 256;
constexpr int NT = 512;
constexpr int NV = 32;

__device__ __forceinline__ float sigmoidf_(float x){ return 1.0f/(1.0f+__expf(-x)); }
__device__ __forceinline__ float tanhf_(float x){ return 1.0f - 2.0f/(__expf(2.0f*x)+1.0f); }

// ---------------- stats + x_comp ----------------
__global__ __launch_bounds__(256) void k_stats(
    const float* __restrict__ values, const float* __restrict__ masks,
    const int* __restrict__ lengths,
    float* __restrict__ x_comp, float* __restrict__ stats)
{
  const int b = blockIdx.x;
  const int v = threadIdx.x & 31;
  const int g = threadIdx.x >> 5;
  const int len = lengths[b];
  const float* vb = values + (size_t)b*NT*NV;
  const float* mb = masks  + (size_t)b*NT*NV;
  float* xb = x_comp + (size_t)b*NT*NV;
  float s_m=0.f, s_mv=0.f, s_v=0.f, s_v2=0.f;
  for (int t=g; t<NT; t+=8){
    float val = vb[t*NV+v];
    float m   = mb[t*NV+v];
    float xp  = (t==0) ? vb[v] : vb[(t-1)*NV+v];
    float pm  = (t<len) ? 1.0f : 0.0f;
    xb[t*NV+v] = (m*val + (1.0f-m)*xp)*pm;
    s_m += m; s_mv += m*val; s_v += val; s_v2 += val*val;
  }
  __shared__ float red[4][8][32];
  red[0][g][v]=s_m; red[1][g][v]=s_mv; red[2][g][v]=s_v; red[3][g][v]=s_v2;
  __syncthreads();
  if (g==0){
    float a0=0,a1=0,a2=0,a3=0;
    #pragma unroll
    for(int i=0;i<8;i++){ a0+=red[0][i][v]; a1+=red[1][i][v]; a2+=red[2][i][v]; a3+=red[3][i][v]; }
    float msum = fmaxf(a0, 1.0f);
    float mean = a1/msum;
    float dss  = a3 - 2.0f*mean*a2 + (float)NT*mean*mean;
    float var  = (msum > 1.0f) ? dss/(msum-1.0f) : 0.0f;
    float sd   = sqrtf(fmaxf(var, 0.0f));
    float miss = 1.0f - a0 / fmaxf((float)len, 1.0f);
    float* st = stats + b*97;
    if (v==0) st[0] = (float)len;
    st[1+v]=mean; st[33+v]=sd; st[65+v]=miss;
  }
}

// ---------------- context MLP ----------------
__global__ __launch_bounds__(64) void k_cmlp(
    const float* __restrict__ stats,
    const float* __restrict__ W1, const float* __restrict__ b1,
    const float* __restrict__ W2, const float* __restrict__ b2,
    float* __restrict__ ctx)
{
  const int b = blockIdx.x;
  const int j = threadIdx.x;
  __shared__ float st[97];
  __shared__ float hm[64];
  for (int k=j; k<97; k+=64) st[k] = stats[b*97+k];
  __syncthreads();
  float a0=b1[j], a1=0.f, a2=0.f, a3=0.f;
  #pragma unroll
  for (int k=0; k<96; k+=4){
    a0 += st[k]*W1[j*97+k];     a1 += st[k+1]*W1[j*97+k+1];
    a2 += st[k+2]*W1[j*97+k+2]; a3 += st[k+3]*W1[j*97+k+3];
  }
  a0 += st[96]*W1[j*97+96];
  hm[j] = fmaxf((a0+a1)+(a2+a3), 0.0f);
  __syncthreads();
  if (j < 32){
    float c0_=b2[j], c1=0.f, c2=0.f, c3=0.f;
    #pragma unroll
    for (int k=0;k<64;k+=4){
      c0_ += hm[k]*W2[j*64+k];    c1 += hm[k+1]*W2[j*64+k+1];
      c2 += hm[k+2]*W2[j*64+k+2]; c3 += hm[k+3]*W2[j*64+k+3];
    }
    ctx[b*64+j] = (c0_+c1)+(c2+c3);
  }
}

// ---------------- GRU scan (one block per batch element) ----------------
__global__ __launch_bounds__(96) void k_gru(
    const float* __restrict__ x_comp, const float* __restrict__ rain_f,
    const float* __restrict__ rain_bw, const int* __restrict__ lengths,
    const float* __restrict__ Wih, const float* __restrict__ Whh,
    const float* __restrict__ bih, const float* __restrict__ bhh,
    float* __restrict__ ctx)
{
  const int b = blockIdx.x;
  const int j = threadIdx.x;
  int len = lengths[b]; if (len > NT) len = NT;
  float wih[96];
  #pragma unroll
  for (int k=0;k<96;k++) wih[k] = Wih[j*96+k];
  float whh[32];
  #pragma unroll
  for (int k=0;k<32;k++) whh[k] = Whh[j*32+k];
  const float bi = bih[j], bh = bhh[j];
  __shared__ float h_lds[32];
  __shared__ float gi_lds[96];
  __shared__ float gh_lds[96];
  if (j < 32) h_lds[j] = 0.0f;
  __syncthreads();
  const float* xc = x_comp + (size_t)b*NT*NV;
  const float* rf = rain_f + (size_t)b*NT*NV;
  const float* rb = rain_bw + (size_t)b*NT*NV;
  for (int t=0; t<len; ++t){
    const float* x0 = xc + t*NV;
    const float* x1 = rf + t*NV;
    const float* x2 = rb + t*NV;
    float ai0=bi, ai1=0.f, ai2=0.f, ai3=0.f;
    #pragma unroll
    for (int k=0;k<32;k+=4){
      ai0 += x0[k]*wih[k];     ai1 += x0[k+1]*wih[k+1];
      ai2 += x0[k+2]*wih[k+2]; ai3 += x0[k+3]*wih[k+3];
    }
    #pragma unroll
    for (int k=0;k<32;k+=4){
      ai0 += x1[k]*wih[32+k];   ai1 += x1[k+1]*wih[33+k];
      ai2 += x1[k+2]*wih[34+k]; ai3 += x1[k+3]*wih[35+k];
    }
    #pragma unroll
    for (int k=0;k<32;k+=4){
      ai0 += x2[k]*wih[64+k];   ai1 += x2[k+1]*wih[65+k];
      ai2 += x2[k+2]*wih[66+k]; ai3 += x2[k+3]*wih[67+k];
    }
    float ah0=bh, ah1=0.f, ah2=0.f, ah3=0.f;
    #pragma unroll
    for (int k=0;k<32;k+=4){
      ah0 += h_lds[k]*whh[k];     ah1 += h_lds[k+1]*whh[k+1];
      ah2 += h_lds[k+2]*whh[k+2]; ah3 += h_lds[k+3]*whh[k+3];
    }
    gi_lds[j] = (ai0+ai1)+(ai2+ai3);
    gh_lds[j] = (ah0+ah1)+(ah2+ah3);
    __syncthreads();
    if (j < 32){
      float r = sigmoidf_(gi_lds[j] + gh_lds[j]);
      float z = sigmoidf_(gi_lds[32+j] + gh_lds[32+j]);
      float n = tanhf_(gi_lds[64+j] + r*gh_lds[64+j]);
      h_lds[j] = (1.0f - z)*n + z*h_lds[j];
    }
    __syncthreads();
  }
  if (j < 32) ctx[b*64 + 32 + j] = h_lds[j];
}

// ---------------- init: h0/c0, ctx-part of LSTM gates, hidden seeds ----------------
__global__ __launch_bounds__(256) void k_init(
    const float* __restrict__ ctx,
    const float* __restrict__ initW, const float* __restrict__ initb,
    const float* __restrict__ WihF, const float* __restrict__ bihF, const float* __restrict__ bhhF,
    const float* __restrict__ WihB, const float* __restrict__ bihB, const float* __restrict__ bhhB,
    float* __restrict__ h0, float* __restrict__ c0,
    float* __restrict__ cgF, float* __restrict__ cgB,
    float* __restrict__ hidden)
{
  const int b = blockIdx.x;
  const int j = threadIdx.x;
  __shared__ float cv[64];
  if (j < 64) cv[j] = ctx[b*64+j];
  __syncthreads();
  {
    float f0=bihF[j]+bhhF[j], f1=0.f, f2=0.f, f3=0.f;
    float g0=bihB[j]+bhhB[j], g1=0.f, g2=0.f, g3=0.f;
    #pragma unroll
    for (int k=0;k<64;k+=4){
      f0 += cv[k]*WihF[j*128+64+k];   f1 += cv[k+1]*WihF[j*128+65+k];
      f2 += cv[k+2]*WihF[j*128+66+k]; f3 += cv[k+3]*WihF[j*128+67+k];
      g0 += cv[k]*WihB[j*128+64+k];   g1 += cv[k+1]*WihB[j*128+65+k];
      g2 += cv[k+2]*WihB[j*128+66+k]; g3 += cv[k+3]*WihB[j*128+67+k];
    }
    cgF[b*256+j] = (f0+f1)+(f2+f3);
    cgB[b*256+j] = (g0+g1)+(g2+g3);
  }
  if (j < 128){
    float a0=initb[j], a1=0.f, a2=0.f, a3=0.f;
    #pragma unroll
    for (int k=0;k<64;k+=4){
      a0 += cv[k]*initW[j*64+k];     a1 += cv[k+1]*initW[j*64+k+1];
      a2 += cv[k+2]*initW[j*64+k+2]; a3 += cv[k+3]*initW[j*64+k+3];
    }
    float hv = (a0+a1)+(a2+a3);
    h0[b*128+j] = hv;
    c0[b*128+j] = tanhf_(hv);
    if (j < 64) hidden[(size_t)b*NT*128 + j] = hv;                               // fwd seed t=0
    else        hidden[(size_t)b*NT*128 + (size_t)(NT-1)*128 + 64 + (j-64)] = hv; // bwd seed t=T-1
  }
}

// ---------------- LSTM scans (block = (b, dir)) ----------------
__global__ __launch_bounds__(256,2) void k_lstm(
    const float* __restrict__ x_comp, const float* __restrict__ masks,
    const float* __restrict__ WihF, const float* __restrict__ WhhF,
    const float* __restrict__ WihB, const float* __restrict__ WhhB,
    const float* __restrict__ cgF, const float* __restrict__ cgB,
    const float* __restrict__ h0, const float* __restrict__ c0,
    const int* __restrict__ lengths,
    float* __restrict__ hidden)
{
  const int b = blockIdx.x;
  const int dir = blockIdx.y;
  const int j = threadIdx.x;
  const float* Wih = dir ? WihB : WihF;
  const float* Whh = dir ? WhhB : WhhF;
  const float* cgp = dir ? cgB : cgF;
  float wx[64];
  #pragma unroll
  for (int k=0;k<64;k++) wx[k] = Wih[j*128+k];
  float wh[64];
  #pragma unroll
  for (int k=0;k<64;k++) wh[k] = Whh[j*64+k];
  const float cg = cgp[b*256+j];
  __shared__ float h_lds[64];
  __shared__ float g_lds[256];
  float c = 0.0f;
  if (j < 64){
    h_lds[j] = h0[b*128 + dir*64 + j];
    c        = c0[b*128 + dir*64 + j];
  }
  __syncthreads();
  const int len = lengths[b];
  int nsteps = NT-1;
  if (dir == 0){
    int e = len - 1; if (e < 0) e = 0;
    if (e < nsteps) nsteps = e;   // outputs past len are zeroed by padding mask
  }
  const float* xc = x_comp + (size_t)b*NT*NV;
  const float* mk = masks  + (size_t)b*NT*NV;
  float* hout = hidden + (size_t)b*NT*128 + dir*64;
  for (int s=0; s<nsteps; ++s){
    const int t    = dir ? (NT-1-s) : s;
    const int outt = dir ? (t-1)    : (s+1);
    const float* xr = xc + t*NV;
    const float* mr = mk + t*NV;
    float a0=cg, a1=0.f, a2=0.f, a3=0.f;
    #pragma unroll
    for (int k=0;k<32;k+=4){
      a0 += xr[k]*wx[k];     a1 += xr[k+1]*wx[k+1];
      a2 += xr[k+2]*wx[k+2]; a3 += xr[k+3]*wx[k+3];
    }
    #pragma unroll
    for (int k=0;k<32;k+=4){
      a0 += mr[k]*wx[32+k];   a1 += mr[k+1]*wx[33+k];
      a2 += mr[k+2]*wx[34+k]; a3 += mr[k+3]*wx[35+k];
    }
    #pragma unroll
    for (int k=0;k<64;k+=4){
      a0 += h_lds[k]*wh[k];     a1 += h_lds[k+1]*wh[k+1];
      a2 += h_lds[k+2]*wh[k+2]; a3 += h_lds[k+3]*wh[k+3];
    }
    g_lds[j] = (a0+a1)+(a2+a3);
    __syncthreads();
    if (j < 64){
      float gi = g_lds[j], gf = g_lds[64+j], gg = g_lds[128+j], go = g_lds[192+j];
      c = sigmoidf_(gf)*c + sigmoidf_(gi)*tanhf_(gg);
      float hh = sigmoidf_(go)*tanhf_(c);
      h_lds[j] = hh;
      hout[(size_t)outt*128 + j] = hh;
    }
    __syncthreads();
  }
}

// ---------------- feature-regression path ----------------
__global__ __launch_bounds__(256,2) void k_feat(
    const float* __restrict__ x_comp,
    const float* __restrict__ feat_W, const float* __restrict__ feat_b,
    const float* __restrict__ nl1_W, const float* __restrict__ nl1_b,
    const float* __restrict__ nl2_W, const float* __restrict__ nl2_b,
    float* __restrict__ feat_imp)
{
  const int tid = threadIdx.x;
  const int lane = tid & 31;   // = h in pass1, = g in pass2
  const int ig = tid >> 5;     // 0..7
  float wm[4][32];
  #pragma unroll
  for (int q=0;q<4;q++){
    const int i = ig + 8*q;
    #pragma unroll
    for (int v=0;v<32;v++){
      float w = feat_W[((size_t)(i*32)+lane)*32 + v];
      wm[q][v] = (v==i) ? 0.0f : w;
    }
  }
  float fb[4];
  #pragma unroll
  for (int q=0;q<4;q++) fb[q] = feat_b[(ig+8*q)*32 + lane];
  float nl1row[32];
  #pragma unroll
  for (int h=0;h<32;h++) nl1row[h] = nl1_W[lane*32+h];
  const float n1b = nl1_b[lane];
  const float n2w = nl2_W[lane];
  const float n2b = nl2_b[0];
  __shared__ float hid[32][36];
  const int NP = NB*NT;
  for (int r = blockIdx.x; r < NP; r += gridDim.x){
    const float* xp = x_comp + (size_t)r*32;
    float a[4] = {fb[0],fb[1],fb[2],fb[3]};
    #pragma unroll
    for (int v=0;v<32;v++){
      float xv = xp[v];
      a[0] += xv*wm[0][v]; a[1] += xv*wm[1][v]; a[2] += xv*wm[2][v]; a[3] += xv*wm[3][v];
    }
    #pragma unroll
    for (int q=0;q<4;q++) hid[ig+8*q][lane] = fmaxf(a[q], 0.0f);
    __syncthreads();
    float z0=n1b, z1=n1b, z2=n1b, z3=n1b;
    #pragma unroll
    for (int h=0; h<32; h+=4){
      float4 v0 = *(const float4*)&hid[ig][h];
      float4 v1 = *(const float4*)&hid[ig+8][h];
      float4 v2 = *(const float4*)&hid[ig+16][h];
      float4 v3 = *(const float4*)&hid[ig+24][h];
      z0 += v0.x*nl1row[h] + v0.y*nl1row[h+1] + v0.z*nl1row[h+2] + v0.w*nl1row[h+3];
      z1 += v1.x*nl1row[h] + v1.y*nl1row[h+1] + v1.z*nl1row[h+2] + v1.w*nl1row[h+3];
      z2 += v2.x*nl1row[h] + v2.y*nl1row[h+1] + v2.z*nl1row[h+2] + v2.w*nl1row[h+3];
      z3 += v3.x*nl1row[h] + v3.y*nl1row[h+1] + v3.z*nl1row[h+2] + v3.w*nl1row[h+3];
    }
    float cr[4];
    cr[0]=fmaxf(z0,0.f)*n2w; cr[1]=fmaxf(z1,0.f)*n2w; cr[2]=fmaxf(z2,0.f)*n2w; cr[3]=fmaxf(z3,0.f)*n2w;
    #pragma unroll
    for (int off=16; off>0; off>>=1){
      #pragma unroll
      for (int q=0;q<4;q++) cr[q] += __shfl_xor(cr[q], off, 32);
    }
    if (lane == 0){
      #pragma unroll
      for (int q=0;q<4;q++) feat_imp[(size_t)r*32 + ig + 8*q] = cr[q] + n2b;
    }
    __syncthreads();
  }
}

// ---------------- rnn_imp GEMM + fuse + final ----------------
__global__ __launch_bounds__(256,2) void k_final(
    const float* __restrict__ values, const float* __restrict__ masks,
    const float* __restrict__ feat_imp, const float* __restrict__ hidden,
    const float* __restrict__ rimp_W, const float* __restrict__ rimp_b,
    const float* __restrict__ fuse_W, const float* __restrict__ fuse_b,
    const int* __restrict__ lengths, float* __restrict__ out)
{
  const int tid = threadIdx.x, v = tid & 31, grp = tid >> 5;
  float wv[128];
  #pragma unroll
  for (int k=0;k<128;k++) wv[k] = rimp_W[v*128+k];
  float fw2[32];
  #pragma unroll
  for (int k=0;k<32;k++) fw2[k] = fuse_W[v*64+32+k];
  float fconst = fuse_b[v];
  #pragma unroll
  for (int k=0;k<32;k++) fconst += fuse_W[v*64+k];   // gamma == 1 contribution
  const float rbias = rimp_b[v];
  __shared__ float hrow[8][128];
  const int NOCT = (NB*NT)/8;
  for (int oc = blockIdx.x; oc < NOCT; oc += gridDim.x){
    const size_t base = (size_t)oc*8;
    __syncthreads();
    ((float4*)hrow)[tid] = ((const float4*)(hidden + base*128))[tid];
    __syncthreads();
    const size_t r = base + grp;
    const int b = (int)(r >> 9);   // T = 512
    const int t = (int)(r & 511);
    const int len = lengths[b];
    float a0=rbias, a1=0.f, a2=0.f, a3=0.f;
    #pragma unroll
    for (int k=0;k<128;k+=4){
      float4 hv = *(const float4*)&hrow[grp][k];
      a0 += hv.x*wv[k]; a1 += hv.y*wv[k+1]; a2 += hv.z*wv[k+2]; a3 += hv.w*wv[k+3];
    }
    const float rimp = (a0+a1)+(a2+a3);
    const float* mrow = masks + r*32;
    float acc = fconst;
    #pragma unroll
    for (int k=0;k<32;k++) acc += mrow[k]*fw2[k];
    const float beta = sigmoidf_(acc);
    const float fi = feat_imp[r*32+v];
    const float m  = mrow[v];
    const float val= values[r*32+v];
    const float fz = beta*fi + (1.0f-beta)*rimp;
    float o = m*val + (1.0f-m)*fz;
    out[r*32+v] = (t < len) ? o : 0.0f;
  }
}

extern "C" void kernel_launch(void* const* d_in, const int* in_sizes, int n_in,
                              void* d_out, int out_size, void* d_ws, size_t ws_size,
                              hipStream_t stream) {
  const float* values   = (const float*)d_in[0];
  const float* masks    = (const float*)d_in[1];
  const float* rain_f   = (const float*)d_in[2];
  const float* rain_b   = (const float*)d_in[3];
  const float* cmlp_W1  = (const float*)d_in[4];
  const float* cmlp_b1  = (const float*)d_in[5];
  const float* cmlp_W2  = (const float*)d_in[6];
  const float* cmlp_b2  = (const float*)d_in[7];
  const float* gru_Wih  = (const float*)d_in[8];
  const float* gru_Whh  = (const float*)d_in[9];
  const float* gru_bih  = (const float*)d_in[10];
  const float* gru_bhh  = (const float*)d_in[11];
  const float* init_W   = (const float*)d_in[12];
  const float* init_b   = (const float*)d_in[13];
  const float* lstmf_Wih= (const float*)d_in[14];
  const float* lstmf_Whh= (const float*)d_in[15];
  const float* lstmf_bih= (const float*)d_in[16];
  const float* lstmf_bhh= (const float*)d_in[17];
  const float* lstmb_Wih= (const float*)d_in[18];
  const float* lstmb_Whh= (const float*)d_in[19];
  const float* lstmb_bih= (const float*)d_in[20];
  const float* lstmb_bhh= (const float*)d_in[21];
  const float* rimp_W   = (const float*)d_in[22];
  const float* rimp_b   = (const float*)d_in[23];
  const float* feat_W   = (const float*)d_in[24];
  const float* feat_b   = (const float*)d_in[25];
  const float* nl1_W    = (const float*)d_in[26];
  const float* nl1_b    = (const float*)d_in[27];
  const float* nl2_W    = (const float*)d_in[28];
  const float* nl2_b    = (const float*)d_in[29];
  const float* fuse_W   = (const float*)d_in[30];
  const float* fuse_b   = (const float*)d_in[31];
  const int*   lengths  = (const int*)d_in[32];
  float* out = (float*)d_out;

  float* ws       = (float*)d_ws;
  float* x_comp   = ws;                                   // B*T*V
  float* stats    = x_comp + (size_t)NB*NT*NV;            // B*97
  float* ctx      = stats + NB*97;                        // B*64
  float* h0       = ctx + NB*64;                          // B*128
  float* c0      = h0 + NB*128;                           // B*128
  float* cgF      = c0 + NB*128;                          // B*256
  float* cgB      = cgF + NB*256;                         // B*256
  float* hidden   = cgB + NB*256;                         // B*T*128
  float* feat_imp = hidden + (size_t)NB*NT*128;           // B*T*V
  // total ~25.4M floats ~= 102 MB

  k_stats<<<NB, 256, 0, stream>>>(values, masks, lengths, x_comp, stats);
  k_feat<<<2048, 256, 0, stream>>>(x_comp, feat_W, feat_b, nl1_W, nl1_b, nl2_W, nl2_b, feat_imp);
  k_cmlp<<<NB, 64, 0, stream>>>(stats, cmlp_W1, cmlp_b1, cmlp_W2, cmlp_b2, ctx);
  k_gru<<<NB, 96, 0, stream>>>(x_comp, rain_f, rain_b, lengths, gru_Wih, gru_Whh, gru_bih, gru_bhh, ctx);
  k_init<<<NB, 256, 0, stream>>>(ctx, init_W, init_b,
                                 lstmf_Wih, lstmf_bih, lstmf_bhh,
                                 lstmb_Wih, lstmb_bih, lstmb_bhh,
                                 h0, c0, cgF, cgB, hidden);
  dim3 lgrid(NB, 2);
  k_lstm<<<lgrid, 256, 0, stream>>>(x_comp, masks,
                                    lstmf_Wih, lstmf_Whh, lstmb_Wih, lstmb_Whh,
                                    cgF, cgB, h0, c0, lengths, hidden);
  k_final<<<2048, 256, 0, stream>>>(values, masks, feat_imp, hidden,
                                    rimp_W, rimp_b, fuse_W, fuse_b, lengths, out);
}

// Round 2
// 1737.888 us; speedup vs baseline: 1.2719x; 1.2719x over previous
//
#include <hip/hip_runtime.h>
#include <cstddef>

constexpr int NB = 256;
constexpr int NT = 512;
constexpr int NV = 32;

__device__ __forceinline__ float sigmoidf_(float x){ return 1.0f/(1.0f+__expf(-x)); }
__device__ __forceinline__ float tanhf_(float x){ return 1.0f - 2.0f/(__expf(2.0f*x)+1.0f); }
__device__ __forceinline__ float hsum4_(const float4 a){ return (a.x+a.y)+(a.z+a.w); }

// ---------------- stats + x_comp ----------------
__global__ __launch_bounds__(256) void k_stats(
    const float* __restrict__ values, const float* __restrict__ masks,
    const int* __restrict__ lengths,
    float* __restrict__ x_comp, float* __restrict__ stats)
{
  const int b = blockIdx.x;
  const int v = threadIdx.x & 31;
  const int g = threadIdx.x >> 5;
  const int len = lengths[b];
  const float* vb = values + (size_t)b*NT*NV;
  const float* mb = masks  + (size_t)b*NT*NV;
  float* xb = x_comp + (size_t)b*NT*NV;
  float s_m=0.f, s_mv=0.f, s_v=0.f, s_v2=0.f;
  for (int t=g; t<NT; t+=8){
    float val = vb[t*NV+v];
    float m   = mb[t*NV+v];
    float xp  = (t==0) ? vb[v] : vb[(t-1)*NV+v];
    float pm  = (t<len) ? 1.0f : 0.0f;
    xb[t*NV+v] = (m*val + (1.0f-m)*xp)*pm;
    s_m += m; s_mv += m*val; s_v += val; s_v2 += val*val;
  }
  __shared__ float red[4][8][32];
  red[0][g][v]=s_m; red[1][g][v]=s_mv; red[2][g][v]=s_v; red[3][g][v]=s_v2;
  __syncthreads();
  if (g==0){
    float a0=0,a1=0,a2=0,a3=0;
    #pragma unroll
    for(int i=0;i<8;i++){ a0+=red[0][i][v]; a1+=red[1][i][v]; a2+=red[2][i][v]; a3+=red[3][i][v]; }
    float msum = fmaxf(a0, 1.0f);
    float mean = a1/msum;
    float dss  = a3 - 2.0f*mean*a2 + (float)NT*mean*mean;
    float var  = (msum > 1.0f) ? dss/(msum-1.0f) : 0.0f;
    float sd   = sqrtf(fmaxf(var, 0.0f));
    float miss = 1.0f - a0 / fmaxf((float)len, 1.0f);
    float* st = stats + b*97;
    if (v==0) st[0] = (float)len;
    st[1+v]=mean; st[33+v]=sd; st[65+v]=miss;
  }
}

// ---------------- context MLP ----------------
__global__ __launch_bounds__(64) void k_cmlp(
    const float* __restrict__ stats,
    const float* __restrict__ W1, const float* __restrict__ b1,
    const float* __restrict__ W2, const float* __restrict__ b2,
    float* __restrict__ ctx)
{
  const int b = blockIdx.x;
  const int j = threadIdx.x;
  __shared__ float st[97];
  __shared__ float hm[64];
  for (int k=j; k<97; k+=64) st[k] = stats[b*97+k];
  __syncthreads();
  float a0=b1[j], a1=0.f, a2=0.f, a3=0.f;
  #pragma unroll
  for (int k=0; k<96; k+=4){
    a0 += st[k]*W1[j*97+k];     a1 += st[k+1]*W1[j*97+k+1];
    a2 += st[k+2]*W1[j*97+k+2]; a3 += st[k+3]*W1[j*97+k+3];
  }
  a0 += st[96]*W1[j*97+96];
  hm[j] = fmaxf((a0+a1)+(a2+a3), 0.0f);
  __syncthreads();
  if (j < 32){
    float c0_=b2[j], c1=0.f, c2=0.f, c3=0.f;
    #pragma unroll
    for (int k=0;k<64;k+=4){
      c0_ += hm[k]*W2[j*64+k];    c1 += hm[k+1]*W2[j*64+k+1];
      c2 += hm[k+2]*W2[j*64+k+2]; c3 += hm[k+3]*W2[j*64+k+3];
    }
    ctx[b*64+j] = (c0_+c1)+(c2+c3);
  }
}

// ---------------- GRU scan (one block per batch element, 128 threads) ----------------
__global__ __launch_bounds__(128,2) void k_gru(
    const float* __restrict__ x_comp, const float* __restrict__ rain_f,
    const float* __restrict__ rain_bw, const int* __restrict__ lengths,
    const float* __restrict__ Wih, const float* __restrict__ Whh,
    const float* __restrict__ bih, const float* __restrict__ bhh,
    float* __restrict__ ctx)
{
  const int b = blockIdx.x;
  const int j = threadIdx.x;
  int len = lengths[b]; if (len > NT) len = NT;
  float4 wi[24], wh4[8];
  float bi = 0.f, bh = 0.f;
  if (j < 96){
    #pragma unroll
    for (int q=0;q<24;q++) wi[q] = *(const float4*)(Wih + (size_t)j*96 + 4*q);
    #pragma unroll
    for (int q=0;q<8;q++)  wh4[q] = *(const float4*)(Whh + (size_t)j*32 + 4*q);
    bi = bih[j]; bh = bhh[j];
  }
  __shared__ __align__(16) float h_lds[32];
  __shared__ float gi_lds[96];
  __shared__ float gh_lds[96];
  __shared__ __align__(16) float xrow[2][96];
  const float* xc = x_comp + (size_t)b*NT*NV;
  const float* rf = rain_f + (size_t)b*NT*NV;
  const float* rb = rain_bw + (size_t)b*NT*NV;
  if (j < 32) h_lds[j] = 0.0f;
  if (j < 96) xrow[0][j] = (j<32) ? xc[j] : (j<64 ? rf[j-32] : rb[j-64]);
  __syncthreads();
  for (int t=0; t<len; ++t){
    const int cur = t & 1, nxt = cur ^ 1;
    float pf = 0.f;
    const bool dopf = (j < 96) && (t+1 < len);
    if (dopf){
      const int tn = t+1;
      pf = (j<32) ? xc[tn*NV+j] : (j<64 ? rf[tn*NV+j-32] : rb[tn*NV+j-64]);
    }
    if (j < 96){
      float4 ai = {bi, 0.f, 0.f, 0.f};
      #pragma unroll
      for (int q=0;q<24;q++){
        const float4 xv = *(const float4*)&xrow[cur][4*q];
        ai.x += xv.x*wi[q].x; ai.y += xv.y*wi[q].y;
        ai.z += xv.z*wi[q].z; ai.w += xv.w*wi[q].w;
      }
      float4 ah = {bh, 0.f, 0.f, 0.f};
      #pragma unroll
      for (int q=0;q<8;q++){
        const float4 hv = *(const float4*)&h_lds[4*q];
        ah.x += hv.x*wh4[q].x; ah.y += hv.y*wh4[q].y;
        ah.z += hv.z*wh4[q].z; ah.w += hv.w*wh4[q].w;
      }
      gi_lds[j] = hsum4_(ai);
      gh_lds[j] = hsum4_(ah);
      if (dopf) xrow[nxt][j] = pf;
    }
    __syncthreads();
    if (j < 32){
      float r = sigmoidf_(gi_lds[j] + gh_lds[j]);
      float z = sigmoidf_(gi_lds[32+j] + gh_lds[32+j]);
      float n = tanhf_(gi_lds[64+j] + r*gh_lds[64+j]);
      h_lds[j] = (1.0f - z)*n + z*h_lds[j];
    }
    __syncthreads();
  }
  if (j < 32) ctx[b*64 + 32 + j] = h_lds[j];
}

// ---------------- init: h0/c0, ctx-part of LSTM gates, hidden seeds ----------------
__global__ __launch_bounds__(256) void k_init(
    const float* __restrict__ ctx,
    const float* __restrict__ initW, const float* __restrict__ initb,
    const float* __restrict__ WihF, const float* __restrict__ bihF, const float* __restrict__ bhhF,
    const float* __restrict__ WihB, const float* __restrict__ bihB, const float* __restrict__ bhhB,
    float* __restrict__ h0, float* __restrict__ c0,
    float* __restrict__ cgF, float* __restrict__ cgB,
    float* __restrict__ hidden)
{
  const int b = blockIdx.x;
  const int j = threadIdx.x;
  __shared__ __align__(16) float cv[64];
  if (j < 64) cv[j] = ctx[b*64+j];
  __syncthreads();
  {
    float4 f = {bihF[j]+bhhF[j], 0.f, 0.f, 0.f};
    float4 g = {bihB[j]+bhhB[j], 0.f, 0.f, 0.f};
    #pragma unroll
    for (int q=0;q<16;q++){
      const float4 cvv = *(const float4*)&cv[4*q];
      const float4 wf = *(const float4*)(WihF + (size_t)j*128 + 64 + 4*q);
      const float4 wb = *(const float4*)(WihB + (size_t)j*128 + 64 + 4*q);
      f.x += cvv.x*wf.x; f.y += cvv.y*wf.y; f.z += cvv.z*wf.z; f.w += cvv.w*wf.w;
      g.x += cvv.x*wb.x; g.y += cvv.y*wb.y; g.z += cvv.z*wb.z; g.w += cvv.w*wb.w;
    }
    cgF[b*256+j] = hsum4_(f);
    cgB[b*256+j] = hsum4_(g);
  }
  if (j < 128){
    float4 a = {initb[j], 0.f, 0.f, 0.f};
    #pragma unroll
    for (int q=0;q<16;q++){
      const float4 cvv = *(const float4*)&cv[4*q];
      const float4 w  = *(const float4*)(initW + (size_t)j*64 + 4*q);
      a.x += cvv.x*w.x; a.y += cvv.y*w.y; a.z += cvv.z*w.z; a.w += cvv.w*w.w;
    }
    float hv = hsum4_(a);
    h0[b*128+j] = hv;
    c0[b*128+j] = tanhf_(hv);
    if (j < 64) hidden[(size_t)b*NT*128 + j] = hv;                               // fwd seed t=0
    else        hidden[(size_t)b*NT*128 + (size_t)(NT-1)*128 + 64 + (j-64)] = hv; // bwd seed t=T-1
  }
}

// ---------------- LSTM scans (block = (b, dir)) ----------------
__global__ __launch_bounds__(256,2) void k_lstm(
    const float* __restrict__ x_comp, const float* __restrict__ masks,
    const float* __restrict__ WihF, const float* __restrict__ WhhF,
    const float* __restrict__ WihB, const float* __restrict__ WhhB,
    const float* __restrict__ cgF, const float* __restrict__ cgB,
    const float* __restrict__ h0, const float* __restrict__ c0,
    const int* __restrict__ lengths,
    float* __restrict__ hidden)
{
  const int b = blockIdx.x;
  const int dir = blockIdx.y;
  const int j = threadIdx.x;
  const float* Wih = dir ? WihB : WihF;
  const float* Whh = dir ? WhhB : WhhF;
  const float* cgp = dir ? cgB : cgF;
  float4 wx4[16], wh4[16];
  #pragma unroll
  for (int q=0;q<16;q++) wx4[q] = *(const float4*)(Wih + (size_t)j*128 + 4*q);
  #pragma unroll
  for (int q=0;q<16;q++) wh4[q] = *(const float4*)(Whh + (size_t)j*64 + 4*q);
  const float cg = cgp[b*256+j];
  __shared__ __align__(16) float h_lds[64];
  __shared__ float g_lds[256];
  __shared__ __align__(16) float xm[2][64];
  float c = 0.0f;
  if (j < 64){
    h_lds[j] = h0[b*128 + dir*64 + j];
    c        = c0[b*128 + dir*64 + j];
  }
  const int len = lengths[b];
  int nsteps = NT-1;
  if (dir == 0){
    int e = len - 1; if (e < 0) e = 0;
    if (e < nsteps) nsteps = e;   // outputs past len are zeroed by padding mask
  }
  const float* xc = x_comp + (size_t)b*NT*NV;
  const float* mk = masks  + (size_t)b*NT*NV;
  float* hout = hidden + (size_t)b*NT*128 + dir*64;
  const int t0 = dir ? NT-1 : 0;
  if (j < 64 && nsteps > 0) xm[0][j] = (j<32) ? xc[t0*NV+j] : mk[t0*NV+j-32];
  __syncthreads();
  for (int s=0; s<nsteps; ++s){
    const int cur = s & 1, nxt = cur ^ 1;
    float pf = 0.f;
    const bool dopf = (j < 64) && (s+1 < nsteps);
    if (dopf){
      const int tn = dir ? (NT-2-s) : (s+1);
      pf = (j<32) ? xc[tn*NV+j] : mk[tn*NV+j-32];
    }
    float4 acc = {cg, 0.f, 0.f, 0.f};
    #pragma unroll
    for (int q=0;q<16;q++){
      const float4 xv = *(const float4*)&xm[cur][4*q];
      acc.x += xv.x*wx4[q].x; acc.y += xv.y*wx4[q].y;
      acc.z += xv.z*wx4[q].z; acc.w += xv.w*wx4[q].w;
    }
    #pragma unroll
    for (int q=0;q<16;q++){
      const float4 hv = *(const float4*)&h_lds[4*q];
      acc.x += hv.x*wh4[q].x; acc.y += hv.y*wh4[q].y;
      acc.z += hv.z*wh4[q].z; acc.w += hv.w*wh4[q].w;
    }
    g_lds[j] = hsum4_(acc);
    if (dopf) xm[nxt][j] = pf;
    __syncthreads();
    if (j < 64){
      float gi = g_lds[j], gf = g_lds[64+j], gg = g_lds[128+j], go = g_lds[192+j];
      c = sigmoidf_(gf)*c + sigmoidf_(gi)*tanhf_(gg);
      float hh = sigmoidf_(go)*tanhf_(c);
      h_lds[j] = hh;
      const int t    = dir ? (NT-1-s) : s;
      const int outt = dir ? (t-1)    : (s+1);
      hout[(size_t)outt*128 + j] = hh;
    }
    __syncthreads();
  }
}

// ---------------- feature-regression path ----------------
__global__ __launch_bounds__(256,2) void k_feat(
    const float* __restrict__ x_comp,
    const float* __restrict__ feat_W, const float* __restrict__ feat_b,
    const float* __restrict__ nl1_W, const float* __restrict__ nl1_b,
    const float* __restrict__ nl2_W, const float* __restrict__ nl2_b,
    float* __restrict__ feat_imp)
{
  const int tid = threadIdx.x;
  const int lane = tid & 31;   // = h in pass1, = g in pass2
  const int ig = tid >> 5;     // 0..7
  float4 wm4[4][8];
  float fb[4];
  #pragma unroll
  for (int q=0;q<4;q++){
    const int i = ig + 8*q;
    #pragma unroll
    for (int cc=0;cc<8;cc++){
      float4 w = *(const float4*)(feat_W + ((size_t)(i*32)+lane)*32 + 4*cc);
      if (cc == (i>>2)){
        const int sub = i & 3;
        if (sub==0) w.x = 0.f; else if (sub==1) w.y = 0.f;
        else if (sub==2) w.z = 0.f; else w.w = 0.f;
      }
      wm4[q][cc] = w;
    }
    fb[q] = feat_b[i*32 + lane];
  }
  float4 n1r[8];
  #pragma unroll
  for (int cc=0;cc<8;cc++) n1r[cc] = *(const float4*)(nl1_W + lane*32 + 4*cc);
  const float n1b = nl1_b[lane];
  const float n2w = nl2_W[lane];
  const float n2b = nl2_b[0];
  __shared__ __align__(16) float hid[32][36];
  const int NP = NB*NT;
  for (int r = blockIdx.x; r < NP; r += gridDim.x){
    const float* xp = x_comp + (size_t)r*32;
    float4 a0v = {fb[0],0.f,0.f,0.f}, a1v = {fb[1],0.f,0.f,0.f};
    float4 a2v = {fb[2],0.f,0.f,0.f}, a3v = {fb[3],0.f,0.f,0.f};
    #pragma unroll
    for (int cc=0;cc<8;cc++){
      const float4 xv = *(const float4*)(xp + 4*cc);
      a0v.x += xv.x*wm4[0][cc].x; a0v.y += xv.y*wm4[0][cc].y; a0v.z += xv.z*wm4[0][cc].z; a0v.w += xv.w*wm4[0][cc].w;
      a1v.x += xv.x*wm4[1][cc].x; a1v.y += xv.y*wm4[1][cc].y; a1v.z += xv.z*wm4[1][cc].z; a1v.w += xv.w*wm4[1][cc].w;
      a2v.x += xv.x*wm4[2][cc].x; a2v.y += xv.y*wm4[2][cc].y; a2v.z += xv.z*wm4[2][cc].z; a2v.w += xv.w*wm4[2][cc].w;
      a3v.x += xv.x*wm4[3][cc].x; a3v.y += xv.y*wm4[3][cc].y; a3v.z += xv.z*wm4[3][cc].z; a3v.w += xv.w*wm4[3][cc].w;
    }
    hid[ig   ][lane] = fmaxf(hsum4_(a0v), 0.0f);
    hid[ig+8 ][lane] = fmaxf(hsum4_(a1v), 0.0f);
    hid[ig+16][lane] = fmaxf(hsum4_(a2v), 0.0f);
    hid[ig+24][lane] = fmaxf(hsum4_(a3v), 0.0f);
    __syncthreads();
    float z0=n1b, z1=n1b, z2=n1b, z3=n1b;
    #pragma unroll
    for (int cc=0; cc<8; cc++){
      const float4 v0 = *(const float4*)&hid[ig   ][4*cc];
      const float4 v1 = *(const float4*)&hid[ig+8 ][4*cc];
      const float4 v2 = *(const float4*)&hid[ig+16][4*cc];
      const float4 v3 = *(const float4*)&hid[ig+24][4*cc];
      z0 += v0.x*n1r[cc].x + v0.y*n1r[cc].y + v0.z*n1r[cc].z + v0.w*n1r[cc].w;
      z1 += v1.x*n1r[cc].x + v1.y*n1r[cc].y + v1.z*n1r[cc].z + v1.w*n1r[cc].w;
      z2 += v2.x*n1r[cc].x + v2.y*n1r[cc].y + v2.z*n1r[cc].z + v2.w*n1r[cc].w;
      z3 += v3.x*n1r[cc].x + v3.y*n1r[cc].y + v3.z*n1r[cc].z + v3.w*n1r[cc].w;
    }
    float cr0 = fmaxf(z0,0.f)*n2w, cr1 = fmaxf(z1,0.f)*n2w;
    float cr2 = fmaxf(z2,0.f)*n2w, cr3 = fmaxf(z3,0.f)*n2w;
    #pragma unroll
    for (int off=16; off>0; off>>=1){
      cr0 += __shfl_xor(cr0, off, 32);
      cr1 += __shfl_xor(cr1, off, 32);
      cr2 += __shfl_xor(cr2, off, 32);
      cr3 += __shfl_xor(cr3, off, 32);
    }
    if (lane == 0){
      feat_imp[(size_t)r*32 + ig     ] = cr0 + n2b;
      feat_imp[(size_t)r*32 + ig + 8 ] = cr1 + n2b;
      feat_imp[(size_t)r*32 + ig + 16] = cr2 + n2b;
      feat_imp[(size_t)r*32 + ig + 24] = cr3 + n2b;
    }
    __syncthreads();
  }
}

// ---------------- rnn_imp GEMM + fuse + final ----------------
__global__ __launch_bounds__(256,2) void k_final(
    const float* __restrict__ values, const float* __restrict__ masks,
    const float* __restrict__ feat_imp, const float* __restrict__ hidden,
    const float* __restrict__ rimp_W, const float* __restrict__ rimp_b,
    const float* __restrict__ fuse_W, const float* __restrict__ fuse_b,
    const int* __restrict__ lengths, float* __restrict__ out)
{
  const int tid = threadIdx.x, v = tid & 31, grp = tid >> 5;
  float4 wv4[32];
  #pragma unroll
  for (int q=0;q<32;q++) wv4[q] = *(const float4*)(rimp_W + (size_t)v*128 + 4*q);
  float4 fw2_4[8];
  #pragma unroll
  for (int q=0;q<8;q++) fw2_4[q] = *(const float4*)(fuse_W + (size_t)v*64 + 32 + 4*q);
  float fconst = fuse_b[v];
  #pragma unroll
  for (int q=0;q<8;q++) fconst += hsum4_(*(const float4*)(fuse_W + (size_t)v*64 + 4*q)); // gamma==1 part
  const float rbias = rimp_b[v];
  __shared__ __align__(16) float hrow[8][128];
  const int NOCT = (NB*NT)/8;
  for (int oc = blockIdx.x; oc < NOCT; oc += gridDim.x){
    const size_t base = (size_t)oc*8;
    __syncthreads();
    ((float4*)hrow)[tid] = ((const float4*)(hidden + base*128))[tid];
    __syncthreads();
    const size_t r = base + grp;
    const int b = (int)(r >> 9);   // T = 512
    const int t = (int)(r & 511);
    const int len = lengths[b];
    float4 a = {rbias, 0.f, 0.f, 0.f};
    #pragma unroll
    for (int q=0;q<32;q++){
      const float4 hv = *(const float4*)&hrow[grp][4*q];
      a.x += hv.x*wv4[q].x; a.y += hv.y*wv4[q].y;
      a.z += hv.z*wv4[q].z; a.w += hv.w*wv4[q].w;
    }
    const float rimp = hsum4_(a);
    const float* mrow = masks + r*32;
    float4 acc4 = {fconst, 0.f, 0.f, 0.f};
    #pragma unroll
    for (int q=0;q<8;q++){
      const float4 mv = *(const float4*)(mrow + 4*q);
      acc4.x += mv.x*fw2_4[q].x; acc4.y += mv.y*fw2_4[q].y;
      acc4.z += mv.z*fw2_4[q].z; acc4.w += mv.w*fw2_4[q].w;
    }
    const float beta = sigmoidf_(hsum4_(acc4));
    const float fi = feat_imp[r*32+v];
    const float m  = mrow[v];
    const float val= values[r*32+v];
    const float fz = beta*fi + (1.0f-beta)*rimp;
    float o = m*val + (1.0f-m)*fz;
    out[r*32+v] = (t < len) ? o : 0.0f;
  }
}

extern "C" void kernel_launch(void* const* d_in, const int* in_sizes, int n_in,
                              void* d_out, int out_size, void* d_ws, size_t ws_size,
                              hipStream_t stream) {
  const float* values   = (const float*)d_in[0];
  const float* masks    = (const float*)d_in[1];
  const float* rain_f   = (const float*)d_in[2];
  const float* rain_b   = (const float*)d_in[3];
  const float* cmlp_W1  = (const float*)d_in[4];
  const float* cmlp_b1  = (const float*)d_in[5];
  const float* cmlp_W2  = (const float*)d_in[6];
  const float* cmlp_b2  = (const float*)d_in[7];
  const float* gru_Wih  = (const float*)d_in[8];
  const float* gru_Whh  = (const float*)d_in[9];
  const float* gru_bih  = (const float*)d_in[10];
  const float* gru_bhh  = (const float*)d_in[11];
  const float* init_W   = (const float*)d_in[12];
  const float* init_b   = (const float*)d_in[13];
  const float* lstmf_Wih= (const float*)d_in[14];
  const float* lstmf_Whh= (const float*)d_in[15];
  const float* lstmf_bih= (const float*)d_in[16];
  const float* lstmf_bhh= (const float*)d_in[17];
  const float* lstmb_Wih= (const float*)d_in[18];
  const float* lstmb_Whh= (const float*)d_in[19];
  const float* lstmb_bih= (const float*)d_in[20];
  const float* lstmb_bhh= (const float*)d_in[21];
  const float* rimp_W   = (const float*)d_in[22];
  const float* rimp_b   = (const float*)d_in[23];
  const float* feat_W   = (const float*)d_in[24];
  const float* feat_b   = (const float*)d_in[25];
  const float* nl1_W    = (const float*)d_in[26];
  const float* nl1_b    = (const float*)d_in[27];
  const float* nl2_W    = (const float*)d_in[28];
  const float* nl2_b    = (const float*)d_in[29];
  const float* fuse_W   = (const float*)d_in[30];
  const float* fuse_b   = (const float*)d_in[31];
  const int*   lengths  = (const int*)d_in[32];
  float* out = (float*)d_out;

  float* ws       = (float*)d_ws;
  float* x_comp   = ws;                                   // B*T*V
  float* stats    = x_comp + (size_t)NB*NT*NV;            // B*97
  float* ctx      = stats + NB*97;                        // B*64
  float* h0       = ctx + NB*64;                          // B*128
  float* c0      = h0 + NB*128;                           // B*128
  float* cgF      = c0 + NB*128;                          // B*256
  float* cgB      = cgF + NB*256;                         // B*256
  float* hidden   = cgB + NB*256;                         // B*T*128
  float* feat_imp = hidden + (size_t)NB*NT*128;           // B*T*V
  // total ~25.4M floats ~= 102 MB

  k_stats<<<NB, 256, 0, stream>>>(values, masks, lengths, x_comp, stats);
  k_feat<<<2048, 256, 0, stream>>>(x_comp, feat_W, feat_b, nl1_W, nl1_b, nl2_W, nl2_b, feat_imp);
  k_cmlp<<<NB, 64, 0, stream>>>(stats, cmlp_W1, cmlp_b1, cmlp_W2, cmlp_b2, ctx);
  k_gru<<<NB, 128, 0, stream>>>(x_comp, rain_f, rain_b, lengths, gru_Wih, gru_Whh, gru_bih, gru_bhh, ctx);
  k_init<<<NB, 256, 0, stream>>>(ctx, init_W, init_b,
                                 lstmf_Wih, lstmf_bih, lstmf_bhh,
                                 lstmb_Wih, lstmb_bih, lstmb_bhh,
                                 h0, c0, cgF, cgB, hidden);
  dim3 lgrid(NB, 2);
  k_lstm<<<lgrid, 256, 0, stream>>>(x_comp, masks,
                                    lstmf_Wih, lstmf_Whh, lstmb_Wih, lstmb_Whh,
                                    cgF, cgB, h0, c0, lengths, hidden);
  k_final<<<2048, 256, 0, stream>>>(values, masks, feat_imp, hidden,
                                    rimp_W, rimp_b, fuse_W, fuse_b, lengths, out);
}

// Round 3
// 1486.315 us; speedup vs baseline: 1.4872x; 1.1693x over previous
//
#include <hip/hip_runtime.h>
#include <cstddef>

constexpr int NB = 256;
constexpr int NT = 512;
constexpr int NV = 32;

__device__ __forceinline__ float sigmoidf_(float x){ return 1.0f/(1.0f+__expf(-x)); }
__device__ __forceinline__ float tanhf_(float x){ return 1.0f - 2.0f/(__expf(2.0f*x)+1.0f); }
__device__ __forceinline__ float hsum4_(const float4 a){ return (a.x+a.y)+(a.z+a.w); }

// ---------------- stats + x_comp ----------------
__global__ __launch_bounds__(256) void k_stats(
    const float* __restrict__ values, const float* __restrict__ masks,
    const int* __restrict__ lengths,
    float* __restrict__ x_comp, float* __restrict__ stats)
{
  const int b = blockIdx.x;
  const int v = threadIdx.x & 31;
  const int g = threadIdx.x >> 5;
  const int len = lengths[b];
  const float* vb = values + (size_t)b*NT*NV;
  const float* mb = masks  + (size_t)b*NT*NV;
  float* xb = x_comp + (size_t)b*NT*NV;
  float s_m=0.f, s_mv=0.f, s_v=0.f, s_v2=0.f;
  for (int t=g; t<NT; t+=8){
    float val = vb[t*NV+v];
    float m   = mb[t*NV+v];
    float xp  = (t==0) ? vb[v] : vb[(t-1)*NV+v];
    float pm  = (t<len) ? 1.0f : 0.0f;
    xb[t*NV+v] = (m*val + (1.0f-m)*xp)*pm;
    s_m += m; s_mv += m*val; s_v += val; s_v2 += val*val;
  }
  __shared__ float red[4][8][32];
  red[0][g][v]=s_m; red[1][g][v]=s_mv; red[2][g][v]=s_v; red[3][g][v]=s_v2;
  __syncthreads();
  if (g==0){
    float a0=0,a1=0,a2=0,a3=0;
    #pragma unroll
    for(int i=0;i<8;i++){ a0+=red[0][i][v]; a1+=red[1][i][v]; a2+=red[2][i][v]; a3+=red[3][i][v]; }
    float msum = fmaxf(a0, 1.0f);
    float mean = a1/msum;
    float dss  = a3 - 2.0f*mean*a2 + (float)NT*mean*mean;
    float var  = (msum > 1.0f) ? dss/(msum-1.0f) : 0.0f;
    float sd   = sqrtf(fmaxf(var, 0.0f));
    float miss = 1.0f - a0 / fmaxf((float)len, 1.0f);
    float* st = stats + b*97;
    if (v==0) st[0] = (float)len;
    st[1+v]=mean; st[33+v]=sd; st[65+v]=miss;
  }
}

// ---------------- context MLP ----------------
__global__ __launch_bounds__(64) void k_cmlp(
    const float* __restrict__ stats,
    const float* __restrict__ W1, const float* __restrict__ b1,
    const float* __restrict__ W2, const float* __restrict__ b2,
    float* __restrict__ ctx)
{
  const int b = blockIdx.x;
  const int j = threadIdx.x;
  __shared__ float st[97];
  __shared__ float hm[64];
  for (int k=j; k<97; k+=64) st[k] = stats[b*97+k];
  __syncthreads();
  float a0=b1[j], a1=0.f, a2=0.f, a3=0.f;
  #pragma unroll
  for (int k=0; k<96; k+=4){
    a0 += st[k]*W1[j*97+k];     a1 += st[k+1]*W1[j*97+k+1];
    a2 += st[k+2]*W1[j*97+k+2]; a3 += st[k+3]*W1[j*97+k+3];
  }
  a0 += st[96]*W1[j*97+96];
  hm[j] = fmaxf((a0+a1)+(a2+a3), 0.0f);
  __syncthreads();
  if (j < 32){
    float c0_=b2[j], c1=0.f, c2=0.f, c3=0.f;
    #pragma unroll
    for (int k=0;k<64;k+=4){
      c0_ += hm[k]*W2[j*64+k];    c1 += hm[k+1]*W2[j*64+k+1];
      c2 += hm[k+2]*W2[j*64+k+2]; c3 += hm[k+3]*W2[j*64+k+3];
    }
    ctx[b*64+j] = (c0_+c1)+(c2+c3);
  }
}

// ---------------- GRU scan: 512 threads, quarter-split of the 128-wide dot ----------------
// q = tid>>7 : q0 -> x (k 0..31, +bih), q1 -> rain_f, q2 -> rain_b, q3 -> h (+bhh)
__global__ __launch_bounds__(512,4) void k_gru(
    const float* __restrict__ x_comp, const float* __restrict__ rain_f,
    const float* __restrict__ rain_bw, const int* __restrict__ lengths,
    const float* __restrict__ Wih, const float* __restrict__ Whh,
    const float* __restrict__ bih, const float* __restrict__ bhh,
    float* __restrict__ ctx)
{
  const int b = blockIdx.x;
  const int tid = threadIdx.x;
  const int j = tid & 127;
  const int q = tid >> 7;
  const bool act = (j < 96);
  int len = lengths[b]; if (len > NT) len = NT;
  const float4 FZ4 = {0.f,0.f,0.f,0.f};
  const float4* W4 = (const float4*)((q < 3) ? (Wih + (size_t)j*96 + q*32)
                                             : (Whh + (size_t)j*32));
  const float4 w0 = act ? W4[0] : FZ4;
  const float4 w1 = act ? W4[1] : FZ4;
  const float4 w2 = act ? W4[2] : FZ4;
  const float4 w3 = act ? W4[3] : FZ4;
  const float4 w4 = act ? W4[4] : FZ4;
  const float4 w5 = act ? W4[5] : FZ4;
  const float4 w6 = act ? W4[6] : FZ4;
  const float4 w7 = act ? W4[7] : FZ4;
  float b0 = 0.f;
  if (act){ if (q == 0) b0 = bih[j]; else if (q == 3) b0 = bhh[j]; }
  __shared__ __align__(16) float h_lds[32];
  __shared__ __align__(16) float xrow[2][96];
  __shared__ float gpart[4][96];
  const float* xc = x_comp + (size_t)b*NT*NV;
  const float* rf = rain_f + (size_t)b*NT*NV;
  const float* rb = rain_bw + (size_t)b*NT*NV;
  if (tid < 32) h_lds[tid] = 0.0f;
  if (tid >= 128 && tid < 224){
    const int jj = tid - 128;
    xrow[0][jj] = (jj<32) ? xc[jj] : (jj<64 ? rf[jj-32] : rb[jj-64]);
  }
  __syncthreads();
  for (int t=0; t<len; ++t){
    const int cur = t & 1;
    float pf = 0.f;
    const bool dopf = (tid >= 128) && (tid < 224) && (t+1 < len);
    if (dopf){
      const int jj = tid - 128, tn = t+1;
      pf = (jj<32) ? xc[tn*NV+jj] : (jj<64 ? rf[tn*NV+jj-32] : rb[tn*NV+jj-64]);
    }
    if (act){
      const float* u = (q < 3) ? (&xrow[cur][0] + q*32) : &h_lds[0];
      float4 acc = {b0, 0.f, 0.f, 0.f};
      #define GSTEP(i) { const float4 uv = *(const float4*)(u + 4*i); \
        acc.x = fmaf(uv.x, w##i.x, acc.x); acc.y = fmaf(uv.y, w##i.y, acc.y); \
        acc.z = fmaf(uv.z, w##i.z, acc.z); acc.w = fmaf(uv.w, w##i.w, acc.w); }
      GSTEP(0) GSTEP(1) GSTEP(2) GSTEP(3) GSTEP(4) GSTEP(5) GSTEP(6) GSTEP(7)
      #undef GSTEP
      gpart[q][j] = hsum4_(acc);
    }
    if (dopf) xrow[cur^1][tid-128] = pf;
    __syncthreads();
    if (tid < 32){
      const float gr = gpart[0][tid]    + gpart[1][tid]    + gpart[2][tid]    + gpart[3][tid];
      const float gz = gpart[0][32+tid] + gpart[1][32+tid] + gpart[2][32+tid] + gpart[3][32+tid];
      const float gni = gpart[0][64+tid] + gpart[1][64+tid] + gpart[2][64+tid];
      const float gnh = gpart[3][64+tid];
      const float r = sigmoidf_(gr);
      const float z = sigmoidf_(gz);
      const float n = tanhf_(gni + r*gnh);
      h_lds[tid] = (1.0f - z)*n + z*h_lds[tid];
    }
    __syncthreads();
  }
  if (tid < 32) ctx[b*64 + 32 + tid] = h_lds[tid];
}

// ---------------- init: h0/c0, ctx-part of LSTM gates, hidden seeds ----------------
__global__ __launch_bounds__(256) void k_init(
    const float* __restrict__ ctx,
    const float* __restrict__ initW, const float* __restrict__ initb,
    const float* __restrict__ WihF, const float* __restrict__ bihF, const float* __restrict__ bhhF,
    const float* __restrict__ WihB, const float* __restrict__ bihB, const float* __restrict__ bhhB,
    float* __restrict__ h0, float* __restrict__ c0,
    float* __restrict__ cgF, float* __restrict__ cgB,
    float* __restrict__ hidden)
{
  const int b = blockIdx.x;
  const int j = threadIdx.x;
  __shared__ __align__(16) float cv[64];
  if (j < 64) cv[j] = ctx[b*64+j];
  __syncthreads();
  {
    float4 f = {bihF[j]+bhhF[j], 0.f, 0.f, 0.f};
    float4 g = {bihB[j]+bhhB[j], 0.f, 0.f, 0.f};
    #pragma unroll
    for (int q=0;q<16;q++){
      const float4 cvv = *(const float4*)&cv[4*q];
      const float4 wf = *(const float4*)(WihF + (size_t)j*128 + 64 + 4*q);
      const float4 wb = *(const float4*)(WihB + (size_t)j*128 + 64 + 4*q);
      f.x += cvv.x*wf.x; f.y += cvv.y*wf.y; f.z += cvv.z*wf.z; f.w += cvv.w*wf.w;
      g.x += cvv.x*wb.x; g.y += cvv.y*wb.y; g.z += cvv.z*wb.z; g.w += cvv.w*wb.w;
    }
    cgF[b*256+j] = hsum4_(f);
    cgB[b*256+j] = hsum4_(g);
  }
  if (j < 128){
    float4 a = {initb[j], 0.f, 0.f, 0.f};
    #pragma unroll
    for (int q=0;q<16;q++){
      const float4 cvv = *(const float4*)&cv[4*q];
      const float4 w  = *(const float4*)(initW + (size_t)j*64 + 4*q);
      a.x += cvv.x*w.x; a.y += cvv.y*w.y; a.z += cvv.z*w.z; a.w += cvv.w*w.w;
    }
    float hv = hsum4_(a);
    h0[b*128+j] = hv;
    c0[b*128+j] = tanhf_(hv);
    if (j < 64) hidden[(size_t)b*NT*128 + j] = hv;                                // fwd seed t=0
    else        hidden[(size_t)b*NT*128 + (size_t)(NT-1)*128 + 64 + (j-64)] = hv; // bwd seed t=T-1
  }
}

// ---------------- LSTM scans: 512 threads, half-split of the 128-wide dot ----------------
// half = tid>>8 : half0 -> [x(32), mask(32)] via Wih cols 0..63 (+cg), half1 -> h via Whh
__global__ __launch_bounds__(512,4) void k_lstm(
    const float* __restrict__ x_comp, const float* __restrict__ masks,
    const float* __restrict__ WihF, const float* __restrict__ WhhF,
    const float* __restrict__ WihB, const float* __restrict__ WhhB,
    const float* __restrict__ cgF, const float* __restrict__ cgB,
    const float* __restrict__ h0, const float* __restrict__ c0,
    const int* __restrict__ lengths,
    float* __restrict__ hidden)
{
  const int b = blockIdx.x;
  const int dir = blockIdx.y;
  const int tid = threadIdx.x;
  const int j = tid & 255;
  const int half = tid >> 8;
  const float* Wih = dir ? WihB : WihF;
  const float* Whh = dir ? WhhB : WhhF;
  const float4* W4 = (const float4*)(half ? (Whh + (size_t)j*64) : (Wih + (size_t)j*128));
  const float4 w0 = W4[0],  w1 = W4[1],  w2 = W4[2],  w3 = W4[3];
  const float4 w4 = W4[4],  w5 = W4[5],  w6 = W4[6],  w7 = W4[7];
  const float4 w8 = W4[8],  w9 = W4[9],  w10 = W4[10], w11 = W4[11];
  const float4 w12 = W4[12], w13 = W4[13], w14 = W4[14], w15 = W4[15];
  const float cg0 = half ? 0.0f : (dir ? cgB : cgF)[b*256 + j];
  __shared__ __align__(16) float h_lds[64];
  __shared__ __align__(16) float xm[2][64];
  __shared__ float gpart[2][256];
  float c = 0.0f;
  if (tid < 64){
    h_lds[tid] = h0[b*128 + dir*64 + tid];
    c          = c0[b*128 + dir*64 + tid];
  }
  const int len = lengths[b];
  int nsteps = NT-1;
  if (dir == 0){
    int e = len - 1; if (e < 0) e = 0;
    if (e < nsteps) nsteps = e;   // outputs past len are zeroed by padding mask
  }
  const float* xc = x_comp + (size_t)b*NT*NV;
  const float* mk = masks  + (size_t)b*NT*NV;
  float* hout = hidden + (size_t)b*NT*128 + dir*64;
  const int t0 = dir ? NT-1 : 0;
  if (tid >= 448){
    const int jj = tid - 448;
    xm[0][jj] = (jj<32) ? xc[t0*NV+jj] : mk[t0*NV+jj-32];
  }
  __syncthreads();
  for (int s=0; s<nsteps; ++s){
    const int cur = s & 1;
    float pf = 0.f;
    const bool dopf = (tid >= 448) && (s+1 < nsteps);
    if (dopf){
      const int jj = tid - 448;
      const int tn = dir ? (NT-2-s) : (s+1);
      pf = (jj<32) ? xc[tn*NV+jj] : mk[tn*NV+jj-32];
    }
    const float* u = half ? &h_lds[0] : &xm[cur][0];
    float4 acc = {cg0, 0.f, 0.f, 0.f};
    #define LSTEP(i) { const float4 uv = *(const float4*)(u + 4*i); \
      acc.x = fmaf(uv.x, w##i.x, acc.x); acc.y = fmaf(uv.y, w##i.y, acc.y); \
      acc.z = fmaf(uv.z, w##i.z, acc.z); acc.w = fmaf(uv.w, w##i.w, acc.w); }
    LSTEP(0) LSTEP(1) LSTEP(2) LSTEP(3) LSTEP(4) LSTEP(5) LSTEP(6) LSTEP(7)
    LSTEP(8) LSTEP(9) LSTEP(10) LSTEP(11) LSTEP(12) LSTEP(13) LSTEP(14) LSTEP(15)
    #undef LSTEP
    gpart[half][j] = hsum4_(acc);
    if (dopf) xm[cur^1][tid-448] = pf;
    __syncthreads();
    if (tid < 64){
      const float gi = gpart[0][tid]     + gpart[1][tid];
      const float gf = gpart[0][64+tid]  + gpart[1][64+tid];
      const float gg = gpart[0][128+tid] + gpart[1][128+tid];
      const float go = gpart[0][192+tid] + gpart[1][192+tid];
      c = sigmoidf_(gf)*c + sigmoidf_(gi)*tanhf_(gg);
      const float hh = sigmoidf_(go)*tanhf_(c);
      h_lds[tid] = hh;
      const int t    = dir ? (NT-1-s) : s;
      const int outt = dir ? (t-1)    : (s+1);
      hout[(size_t)outt*128 + tid] = hh;
    }
    __syncthreads();
  }
}

// ---------------- feature-regression path: 512 threads, 2 output rows per thread ----------------
__global__ __launch_bounds__(512,4) void k_feat(
    const float* __restrict__ x_comp,
    const float* __restrict__ feat_W, const float* __restrict__ feat_b,
    const float* __restrict__ nl1_W, const float* __restrict__ nl1_b,
    const float* __restrict__ nl2_W, const float* __restrict__ nl2_b,
    float* __restrict__ feat_imp)
{
  const int tid = threadIdx.x;
  const int lane = tid & 31;   // h-index (pass1), g-index (pass2)
  const int ig = tid >> 4 >> 1; // tid>>5: 0..15
  const int i0 = ig, i1 = ig + 16;
  // masked feat_W rows for (i0,lane) and (i1,lane): 8+8 named float4
  const float4* A4 = (const float4*)(feat_W + ((size_t)(i0*32)+lane)*32);
  const float4* B4 = (const float4*)(feat_W + ((size_t)(i1*32)+lane)*32);
  #define LOADW(nm, P4, ii, cc) float4 nm = P4[cc]; \
    if (cc == ((ii)>>2)){ const int sub=(ii)&3; \
      if (sub==0) nm.x=0.f; else if (sub==1) nm.y=0.f; else if (sub==2) nm.z=0.f; else nm.w=0.f; }
  LOADW(a0,A4,i0,0) LOADW(a1,A4,i0,1) LOADW(a2,A4,i0,2) LOADW(a3,A4,i0,3)
  LOADW(a4,A4,i0,4) LOADW(a5,A4,i0,5) LOADW(a6,A4,i0,6) LOADW(a7,A4,i0,7)
  LOADW(b0,B4,i1,0) LOADW(b1,B4,i1,1) LOADW(b2,B4,i1,2) LOADW(b3,B4,i1,3)
  LOADW(b4,B4,i1,4) LOADW(b5,B4,i1,5) LOADW(b6,B4,i1,6) LOADW(b7,B4,i1,7)
  #undef LOADW
  const float fb0 = feat_b[i0*32 + lane];
  const float fb1 = feat_b[i1*32 + lane];
  const float n1b = nl1_b[lane];
  const float n2w = nl2_W[lane];
  const float n2b = nl2_b[0];
  __shared__ __align__(16) float hid[32][36];
  __shared__ __align__(16) float nl1s[32][36];
  if (tid < 256){
    const int rrow = tid >> 3, c4 = (tid & 7) * 4;
    *(float4*)&nl1s[rrow][c4] = *(const float4*)(nl1_W + rrow*32 + c4);
  }
  __syncthreads();
  const int NP = NB*NT;
  for (int r = blockIdx.x; r < NP; r += gridDim.x){
    const float* xp = x_comp + (size_t)r*32;
    float4 acc0 = {fb0, 0.f, 0.f, 0.f};
    float4 acc1 = {fb1, 0.f, 0.f, 0.f};
    #define FST(i, an, bn) { const float4 xv = *(const float4*)(xp + 4*i); \
      acc0.x = fmaf(xv.x, an.x, acc0.x); acc0.y = fmaf(xv.y, an.y, acc0.y); \
      acc0.z = fmaf(xv.z, an.z, acc0.z); acc0.w = fmaf(xv.w, an.w, acc0.w); \
      acc1.x = fmaf(xv.x, bn.x, acc1.x); acc1.y = fmaf(xv.y, bn.y, acc1.y); \
      acc1.z = fmaf(xv.z, bn.z, acc1.z); acc1.w = fmaf(xv.w, bn.w, acc1.w); }
    FST(0,a0,b0) FST(1,a1,b1) FST(2,a2,b2) FST(3,a3,b3)
    FST(4,a4,b4) FST(5,a5,b5) FST(6,a6,b6) FST(7,a7,b7)
    #undef FST
    hid[i0][lane] = fmaxf(hsum4_(acc0), 0.0f);
    hid[i1][lane] = fmaxf(hsum4_(acc1), 0.0f);
    __syncthreads();
    float z0 = n1b, z1 = n1b;
    #pragma unroll
    for (int cc=0; cc<8; cc++){
      const float4 nn = *(const float4*)&nl1s[lane][4*cc];
      const float4 v0 = *(const float4*)&hid[i0][4*cc];
      const float4 v1 = *(const float4*)&hid[i1][4*cc];
      z0 += v0.x*nn.x + v0.y*nn.y + v0.z*nn.z + v0.w*nn.w;
      z1 += v1.x*nn.x + v1.y*nn.y + v1.z*nn.z + v1.w*nn.w;
    }
    float cr0 = fmaxf(z0, 0.f)*n2w;
    float cr1 = fmaxf(z1, 0.f)*n2w;
    #pragma unroll
    for (int off=16; off>0; off>>=1){
      cr0 += __shfl_xor(cr0, off, 32);
      cr1 += __shfl_xor(cr1, off, 32);
    }
    if (lane == 0){
      feat_imp[(size_t)r*32 + i0] = cr0 + n2b;
      feat_imp[(size_t)r*32 + i1] = cr1 + n2b;
    }
    __syncthreads();
  }
}

// ---------------- rnn_imp GEMM + fuse + final: 512 threads, half-split of 128-dot ----------------
__global__ __launch_bounds__(512,4) void k_final(
    const float* __restrict__ values, const float* __restrict__ masks,
    const float* __restrict__ feat_imp, const float* __restrict__ hidden,
    const float* __restrict__ rimp_W, const float* __restrict__ rimp_b,
    const float* __restrict__ fuse_W, const float* __restrict__ fuse_b,
    const int* __restrict__ lengths, float* __restrict__ out)
{
  const int tid = threadIdx.x;
  const int v = tid & 31;
  const int grp = (tid >> 5) & 7;
  const int half = tid >> 8;
  const float4 FZ4 = {0.f,0.f,0.f,0.f};
  const float4* W4 = (const float4*)(rimp_W + (size_t)v*128 + half*64);
  const float4 w0 = W4[0],  w1 = W4[1],  w2 = W4[2],  w3 = W4[3];
  const float4 w4 = W4[4],  w5 = W4[5],  w6 = W4[6],  w7 = W4[7];
  const float4 w8 = W4[8],  w9 = W4[9],  w10 = W4[10], w11 = W4[11];
  const float4 w12 = W4[12], w13 = W4[13], w14 = W4[14], w15 = W4[15];
  // half1 additionally holds the mask-dot weights
  const float4* F4 = (const float4*)(fuse_W + (size_t)v*64 + 32);
  const float4 f0 = half ? F4[0] : FZ4, f1 = half ? F4[1] : FZ4;
  const float4 f2 = half ? F4[2] : FZ4, f3 = half ? F4[3] : FZ4;
  const float4 f4 = half ? F4[4] : FZ4, f5 = half ? F4[5] : FZ4;
  const float4 f6 = half ? F4[6] : FZ4, f7 = half ? F4[7] : FZ4;
  float fconst = 0.f;
  if (!half){
    fconst = fuse_b[v];
    #pragma unroll
    for (int q=0;q<8;q++) fconst += hsum4_(*(const float4*)(fuse_W + (size_t)v*64 + 4*q)); // gamma==1 part
  }
  const float rbias = rimp_b[v];
  __shared__ __align__(16) float hrow[8][128];
  __shared__ float rpart[8][32];
  __shared__ float bpart[8][32];
  const int NOCT = (NB*NT)/8;
  for (int oc = blockIdx.x; oc < NOCT; oc += gridDim.x){
    const size_t base = (size_t)oc*8;
    __syncthreads();
    if (tid < 256) ((float4*)hrow)[tid] = ((const float4*)(hidden + base*128))[tid];
    __syncthreads();
    const size_t r = base + grp;
    float4 a = {half ? 0.f : rbias, 0.f, 0.f, 0.f};
    const float* hb = &hrow[grp][half*64];
    #define RST(i) { const float4 hv = *(const float4*)(hb + 4*i); \
      a.x = fmaf(hv.x, w##i.x, a.x); a.y = fmaf(hv.y, w##i.y, a.y); \
      a.z = fmaf(hv.z, w##i.z, a.z); a.w = fmaf(hv.w, w##i.w, a.w); }
    RST(0) RST(1) RST(2) RST(3) RST(4) RST(5) RST(6) RST(7)
    RST(8) RST(9) RST(10) RST(11) RST(12) RST(13) RST(14) RST(15)
    #undef RST
    if (half){
      rpart[grp][v] = hsum4_(a);
      const float* mrow = masks + r*32;
      float4 acc4 = FZ4;
      #define MST(i) { const float4 mv = *(const float4*)(mrow + 4*i); \
        acc4.x = fmaf(mv.x, f##i.x, acc4.x); acc4.y = fmaf(mv.y, f##i.y, acc4.y); \
        acc4.z = fmaf(mv.z, f##i.z, acc4.z); acc4.w = fmaf(mv.w, f##i.w, acc4.w); }
      MST(0) MST(1) MST(2) MST(3) MST(4) MST(5) MST(6) MST(7)
      #undef MST
      bpart[grp][v] = hsum4_(acc4);
    }
    __syncthreads();
    if (!half){
      const int bb = (int)(r >> 9);   // T = 512
      const int t = (int)(r & 511);
      const int len = lengths[bb];
      const float rimp = hsum4_(a) + rpart[grp][v];
      const float beta = sigmoidf_(fconst + bpart[grp][v]);
      const float fi = feat_imp[r*32+v];
      const float m  = masks[r*32+v];
      const float val= values[r*32+v];
      const float fz = beta*fi + (1.0f-beta)*rimp;
      const float o = m*val + (1.0f-m)*fz;
      out[r*32+v] = (t < len) ? o : 0.0f;
    }
  }
}

extern "C" void kernel_launch(void* const* d_in, const int* in_sizes, int n_in,
                              void* d_out, int out_size, void* d_ws, size_t ws_size,
                              hipStream_t stream) {
  const float* values   = (const float*)d_in[0];
  const float* masks    = (const float*)d_in[1];
  const float* rain_f   = (const float*)d_in[2];
  const float* rain_b   = (const float*)d_in[3];
  const float* cmlp_W1  = (const float*)d_in[4];
  const float* cmlp_b1  = (const float*)d_in[5];
  const float* cmlp_W2  = (const float*)d_in[6];
  const float* cmlp_b2  = (const float*)d_in[7];
  const float* gru_Wih  = (const float*)d_in[8];
  const float* gru_Whh  = (const float*)d_in[9];
  const float* gru_bih  = (const float*)d_in[10];
  const float* gru_bhh  = (const float*)d_in[11];
  const float* init_W   = (const float*)d_in[12];
  const float* init_b   = (const float*)d_in[13];
  const float* lstmf_Wih= (const float*)d_in[14];
  const float* lstmf_Whh= (const float*)d_in[15];
  const float* lstmf_bih= (const float*)d_in[16];
  const float* lstmf_bhh= (const float*)d_in[17];
  const float* lstmb_Wih= (const float*)d_in[18];
  const float* lstmb_Whh= (const float*)d_in[19];
  const float* lstmb_bih= (const float*)d_in[20];
  const float* lstmb_bhh= (const float*)d_in[21];
  const float* rimp_W   = (const float*)d_in[22];
  const float* rimp_b   = (const float*)d_in[23];
  const float* feat_W   = (const float*)d_in[24];
  const float* feat_b   = (const float*)d_in[25];
  const float* nl1_W    = (const float*)d_in[26];
  const float* nl1_b    = (const float*)d_in[27];
  const float* nl2_W    = (const float*)d_in[28];
  const float* nl2_b    = (const float*)d_in[29];
  const float* fuse_W   = (const float*)d_in[30];
  const float* fuse_b   = (const float*)d_in[31];
  const int*   lengths  = (const int*)d_in[32];
  float* out = (float*)d_out;

  float* ws       = (float*)d_ws;
  float* x_comp   = ws;                                   // B*T*V
  float* stats    = x_comp + (size_t)NB*NT*NV;            // B*97
  float* ctx      = stats + NB*97;                        // B*64
  float* h0       = ctx + NB*64;                          // B*128
  float* c0      = h0 + NB*128;                           // B*128
  float* cgF      = c0 + NB*128;                          // B*256
  float* cgB      = cgF + NB*256;                         // B*256
  float* hidden   = cgB + NB*256;                         // B*T*128
  float* feat_imp = hidden + (size_t)NB*NT*128;           // B*T*V
  // total ~25.4M floats ~= 102 MB

  k_stats<<<NB, 256, 0, stream>>>(values, masks, lengths, x_comp, stats);
  k_feat<<<2048, 512, 0, stream>>>(x_comp, feat_W, feat_b, nl1_W, nl1_b, nl2_W, nl2_b, feat_imp);
  k_cmlp<<<NB, 64, 0, stream>>>(stats, cmlp_W1, cmlp_b1, cmlp_W2, cmlp_b2, ctx);
  k_gru<<<NB, 512, 0, stream>>>(x_comp, rain_f, rain_b, lengths, gru_Wih, gru_Whh, gru_bih, gru_bhh, ctx);
  k_init<<<NB, 256, 0, stream>>>(ctx, init_W, init_b,
                                 lstmf_Wih, lstmf_bih, lstmf_bhh,
                                 lstmb_Wih, lstmb_bih, lstmb_bhh,
                                 h0, c0, cgF, cgB, hidden);
  dim3 lgrid(NB, 2);
  k_lstm<<<lgrid, 512, 0, stream>>>(x_comp, masks,
                                    lstmf_Wih, lstmf_Whh, lstmb_Wih, lstmb_Whh,
                                    cgF, cgB, h0, c0, lengths, hidden);
  k_final<<<2048, 512, 0, stream>>>(values, masks, feat_imp, hidden,
                                    rimp_W, rimp_b, fuse_W, fuse_b, lengths, out);
}